// Round 1
// baseline (214.549 us; speedup 1.0000x reference)
//
#include <hip/hip_runtime.h>
#include <hip/hip_bf16.h>
#include <stdint.h>

typedef __attribute__((ext_vector_type(8))) short short8;
typedef __attribute__((ext_vector_type(4))) float floatx4;

#define M_TOT 8192
#define N_TOT 3072
#define K_TOT 1024

__device__ inline unsigned short f2bf(float f) {
    union { float f; unsigned int ui; } v; v.f = f;
    unsigned int x = v.ui;
    unsigned int r = (x + 0x7fffu + ((x >> 16) & 1u)) >> 16; // RNE
    return (unsigned short)r;
}

__device__ inline void gl2lds16(const void* g, void* l) {
    __builtin_amdgcn_global_load_lds(
        (__attribute__((address_space(1))) void*)g,
        (__attribute__((address_space(3))) void*)l,
        16, 0, 0);
}

// ---------------------------------------------------------------------------
// Kernel 0: fp32 -> bf16 convert (for x). n8 = n/8.  (unchanged)
// ---------------------------------------------------------------------------
__global__ __launch_bounds__(256) void cvt_f32_bf16_kernel(
    const float* __restrict__ in, unsigned short* __restrict__ out, int n8)
{
    int i = blockIdx.x * 256 + threadIdx.x;
    if (i >= n8) return;
    const float4* p = (const float4*)in + (size_t)i * 2;
    float4 a = p[0], b = p[1];
    short8 s;
    s[0] = (short)f2bf(a.x); s[1] = (short)f2bf(a.y);
    s[2] = (short)f2bf(a.z); s[3] = (short)f2bf(a.w);
    s[4] = (short)f2bf(b.x); s[5] = (short)f2bf(b.y);
    s[6] = (short)f2bf(b.z); s[7] = (short)f2bf(b.w);
    *(short8*)(out + (size_t)i * 8) = s;
}

// ---------------------------------------------------------------------------
// Kernel 1: rotate W -> filt (bf16).  (unchanged)
// ---------------------------------------------------------------------------
__global__ __launch_bounds__(256) void rotate_w_kernel(
    const float* __restrict__ W,    // [3072,1024] fp32
    const float* __restrict__ qR,   // [8,128,128] fp32
    const float* __restrict__ kR,
    const float* __restrict__ vR,
    unsigned short* __restrict__ Fout)   // [3072,1024] bf16
{
    __shared__ float Rs[128 * 128]; // 64 KB
    __shared__ float Ws[64 * 132];  // 33 KB (stride-132 padded)

    const int tid = threadIdx.x;
    const int o0 = blockIdx.x * 64;
    const int r = blockIdx.y;

    const float* R = (o0 < 1024) ? qR : (o0 < 2048) ? kR : vR;
    R += (size_t)r * 128 * 128;

#pragma unroll
    for (int i = 0; i < 16; ++i) {
        int idx = (i * 256 + tid) * 4;
        *(float4*)(Rs + idx) = *(const float4*)(R + idx);
    }
#pragma unroll
    for (int i = 0; i < 8; ++i) {
        int idx = (i * 256 + tid) * 4;
        int row = idx >> 7;
        int col = idx & 127;
        *(float4*)(Ws + row * 132 + col) =
            *(const float4*)(W + (size_t)(o0 + row) * K_TOT + r * 128 + col);
    }
    __syncthreads();

    const int jg = (tid & 15) * 8;  // j base (0,8,...,120)
    const int ob = tid >> 4;        // 0..15

    float acc[4][8];
#pragma unroll
    for (int a = 0; a < 4; ++a)
#pragma unroll
        for (int b = 0; b < 8; ++b) acc[a][b] = 0.f;

    for (int i = 0; i < 128; ++i) {
        float4 r0 = *(const float4*)(Rs + i * 128 + jg);
        float4 r1 = *(const float4*)(Rs + i * 128 + jg + 4);
        float rv[8] = {r0.x, r0.y, r0.z, r0.w, r1.x, r1.y, r1.z, r1.w};
#pragma unroll
        for (int oo = 0; oo < 4; ++oo) {
            float wv = Ws[(ob + oo * 16) * 132 + i];
#pragma unroll
            for (int t = 0; t < 8; ++t) acc[oo][t] += wv * rv[t];
        }
    }

#pragma unroll
    for (int oo = 0; oo < 4; ++oo) {
        int o = o0 + ob + oo * 16;
        short8 s;
#pragma unroll
        for (int t = 0; t < 8; ++t) s[t] = (short)f2bf(acc[oo][t]);
        *(short8*)(Fout + (size_t)o * K_TOT + r * 128 + jg) = s;
    }
}

// ---------------------------------------------------------------------------
// Kernel 2 (NEW): 256x256x64 8-phase GEMM, out = X @ F^T + bias (fp32 out).
// 512 thr = 8 waves (2M x 4N), per-wave 128x64, mfma_f32_16x16x32_bf16.
// LDS 128 KB dynamic: A[2][256][64] bf16 @0, B[2][256][64] bf16 @32768 elems.
// T2: 16B-block swizzle cb ^= (row&7): pre-swizzled GLOBAL src, linear DMA
//     dest, swizzled ds_read (both-sides rule).
// T3+T4: 4 phases/K-tile, each {ds_read group | stage 1 group (2 gload_lds)
//     | s_barrier | MFMA x16 | s_barrier}; counted vmcnt(4) once per K-tile
//     (2 groups always in flight), drained only at the end.
// Staging groups aligned to quadrant read-groups so prefetch of tile kt+2
// into the live buffer lands only in rows whose reads completed >=1 barrier
// earlier:
//   A-g0 rows {0-63,128-191} (read @phi0)   staged @phi2
//   A-g1 rows {64-127,192-255} (read @phi2) staged @phi1(next tile side)
//   B-g0 rows {0-31,64-95,128-159,192-223} (read @phi0) staged @phi3
//   B-g1 complement (read @phi1)            staged @phi0
// T5: setprio(1) around each MFMA cluster.
// C/D (16x16): col=lane&15, row=(lane>>4)*4+reg  [m89].
// ---------------------------------------------------------------------------
#define GKT 16

__global__ __launch_bounds__(512, 2) void gemm256_kernel(
    const unsigned short* __restrict__ X,  // [8192,1024] bf16
    const unsigned short* __restrict__ F,  // [3072,1024] bf16
    const float* __restrict__ bias,        // [3072] fp32
    float* __restrict__ out)               // [8192,3072] fp32
{
    extern __shared__ unsigned short sm[];

    const int tid = threadIdx.x;
    const int wid = tid >> 6;
    const int l   = tid & 63;
    const int wm  = wid >> 2;   // 0..1
    const int wn  = wid & 3;    // 0..3

    // bijective XCD swizzle: 384 blocks, 384 % 8 == 0
    const int bswz = (blockIdx.x & 7) * 48 + (blockIdx.x >> 3);
    const int m0 = (bswz / 12) * 256;
    const int n0 = (bswz % 12) * 256;

    // ---- staging constants: round = 64 rows x 64 cols = 8 KB, 512 thr x 16B
    const int srow  = tid >> 3;           // 0..63
    const int scb   = tid & 7;            // 16B-block within row (linear dest)
    const int sgcb  = scb ^ (srow & 7);   // pre-swizzled global col-block
    const int sswap = (tid >> 8) << 5;    // +32 rows for B-round upper half

    const unsigned short* Xs = X + (size_t)(m0 + srow) * K_TOT + sgcb * 8;
    const unsigned short* Fs = F + (size_t)(n0 + srow + sswap) * K_TOT + sgcb * 8;
    unsigned short* smA = sm + srow * 64 + scb * 8;
    unsigned short* smB = sm + 32768 + (srow + sswap) * 64 + scb * 8;

#define STAGE_A(bo, rb, kc) gl2lds16(Xs + (size_t)(rb) * K_TOT + (kc), smA + (bo) + (rb) * 64)
#define STAGE_B(bo, rb, kc) gl2lds16(Fs + (size_t)(rb) * K_TOT + (kc), smB + (bo) + (rb) * 64)
#define STAGE_Ag0(bo, kc) { STAGE_A(bo, 0, kc);  STAGE_A(bo, 128, kc); }
#define STAGE_Ag1(bo, kc) { STAGE_A(bo, 64, kc); STAGE_A(bo, 192, kc); }
#define STAGE_Bg0(bo, kc) { STAGE_B(bo, 0, kc);  STAGE_B(bo, 128, kc); }
#define STAGE_Bg1(bo, kc) { STAGE_B(bo, 32, kc); STAGE_B(bo, 160, kc); }
#define BARRIER() asm volatile("s_barrier" ::: "memory")

    // ---- fragment-read constants (swizzled slot = cb_log ^ (row&7), row&7 = l&7)
    const int l15 = l & 15;
    const int s8a = (((l >> 4) + 0) ^ (l & 7)) * 8;   // ks=0 slot (elements)
    const int s8b = (((l >> 4) + 4) ^ (l & 7)) * 8;   // ks=1 slot
    const int paBase = (wm * 128 + l15) * 64;
    const int pbBase = (wn * 64 + l15) * 64;

    floatx4 acc[8][4];
#pragma unroll
    for (int i = 0; i < 8; ++i)
#pragma unroll
        for (int j = 0; j < 4; ++j)
#pragma unroll
            for (int t = 0; t < 4; ++t) acc[i][j][t] = 0.f;

    short8 aF[4][2];       // [mf][ks] for current qm
    short8 bF[2][2][2];    // [qn][nf][ks], both qn halves held across phases

#define RD_A(QM, co) { _Pragma("unroll") for (int mf = 0; mf < 4; ++mf) { \
        const unsigned short* p = sm + (co) + paBase + ((QM) * 4 + mf) * 1024; \
        aF[mf][0] = *(const short8*)(p + s8a); \
        aF[mf][1] = *(const short8*)(p + s8b); } }
#define RD_B(QN, co) { _Pragma("unroll") for (int nf = 0; nf < 2; ++nf) { \
        const unsigned short* p = sm + 32768 + (co) + pbBase + ((QN) * 2 + nf) * 1024; \
        bF[QN][nf][0] = *(const short8*)(p + s8a); \
        bF[QN][nf][1] = *(const short8*)(p + s8b); } }
#define DO_MFMA(QM, QN) { __builtin_amdgcn_s_setprio(1); \
        _Pragma("unroll") for (int mf = 0; mf < 4; ++mf) \
        _Pragma("unroll") for (int nf = 0; nf < 2; ++nf) { \
            acc[(QM)*4+mf][(QN)*2+nf] = __builtin_amdgcn_mfma_f32_16x16x32_bf16( \
                aF[mf][0], bF[QN][nf][0], acc[(QM)*4+mf][(QN)*2+nf], 0, 0, 0); \
            acc[(QM)*4+mf][(QN)*2+nf] = __builtin_amdgcn_mfma_f32_16x16x32_bf16( \
                aF[mf][1], bF[QN][nf][1], acc[(QM)*4+mf][(QN)*2+nf], 0, 0, 0); } \
        __builtin_amdgcn_s_setprio(0); }

    // ---- prologue: tile0 fully + first 2 groups of tile1 (12 loads);
    // vmcnt(4) -> tile0 landed, {Ag0(1),Bg0(1)} in flight.
    STAGE_Ag0(0, 0); STAGE_Bg0(0, 0); STAGE_Bg1(0, 0); STAGE_Ag1(0, 0);
    STAGE_Ag0(16384, 64); STAGE_Bg0(16384, 64);
    asm volatile("s_waitcnt vmcnt(4)" ::: "memory");
    BARRIER();

    for (int kt = 0; kt < GKT; ++kt) {
        const int co = (kt & 1) << 14;   // current buf (element offset)
        const int no = co ^ 16384;       // next buf
        const int kc1 = (kt + 1) * 64;
        const int kc2 = (kt + 2) * 64;

        // phase 0: quadrant (qm=0, qn=0)
        RD_A(0, co); RD_B(0, co);
        if (kt + 1 < GKT) { STAGE_Bg1(no, kc1); }
        BARRIER();
        DO_MFMA(0, 0);
        BARRIER();

        // phase 1: (0,1)  — reuses aF
        RD_B(1, co);
        if (kt + 1 < GKT) { STAGE_Ag1(no, kc1); }
        BARRIER();
        DO_MFMA(0, 1);
        BARRIER();

        // phase 2: (1,0)  — reuses bF[0]; prefetch kt+2 into live buf (safe:
        // A-g0 rows were last read in phase 0, >=1 barrier ago, all waves)
        RD_A(1, co);
        if (kt + 2 < GKT) { STAGE_Ag0(co, kc2); }
        BARRIER();
        DO_MFMA(1, 0);
        BARRIER();

        // phase 3: (1,1)  — reuses aF + bF[1]; counted vmcnt once per K-tile:
        // leaves {Ag0(kt+2), Bg0(kt+2)} = 4 loads in flight across the boundary
        if (kt + 2 < GKT) { STAGE_Bg0(co, kc2); }
        if (kt < GKT - 2) { asm volatile("s_waitcnt vmcnt(4)" ::: "memory"); }
        else              { asm volatile("s_waitcnt vmcnt(0)" ::: "memory"); }
        BARRIER();
        DO_MFMA(1, 1);
        BARRIER();
    }

    // ---- epilogue: bias + direct stores (4 x 64B segments per instruction)
    float bv[4];
#pragma unroll
    for (int nf = 0; nf < 4; ++nf) bv[nf] = bias[n0 + wn * 64 + nf * 16 + l15];

    const int mrow = m0 + wm * 128 + (l >> 4) * 4;
    const int ncol = n0 + wn * 64 + l15;
#pragma unroll
    for (int mf = 0; mf < 8; ++mf)
#pragma unroll
        for (int nf = 0; nf < 4; ++nf) {
            float* po = out + (size_t)(mrow + mf * 16) * N_TOT + ncol + nf * 16;
#pragma unroll
            for (int r = 0; r < 4; ++r)
                po[(size_t)r * N_TOT] = acc[mf][nf][r] + bv[nf];
        }
}

extern "C" void kernel_launch(void* const* d_in, const int* in_sizes, int n_in,
                              void* d_out, int out_size, void* d_ws, size_t ws_size,
                              hipStream_t stream) {
    const float* attn = (const float*)d_in[0]; // [3072,1024] fp32
    const float* bias = (const float*)d_in[1]; // [3072] fp32
    const float* x    = (const float*)d_in[2]; // [4,2048,1024] fp32
    const float* qR   = (const float*)d_in[3]; // [8,128,128] fp32
    const float* kR   = (const float*)d_in[4];
    const float* vR   = (const float*)d_in[5];

    float* out = (float*)d_out; // [4,2048,3072] fp32

    // ws layout: xb [8192*1024] bf16 (16 MB) | filt [3072*1024] bf16 (6 MB)
    unsigned short* xb   = (unsigned short*)d_ws;
    unsigned short* filt = xb + (size_t)M_TOT * K_TOT;

    static bool attr_set = false;
    if (!attr_set) {
        hipFuncSetAttribute((const void*)gemm256_kernel,
                            hipFuncAttributeMaxDynamicSharedMemorySize, 131072);
        attr_set = true;
    }

    const int n8 = (M_TOT * K_TOT) / 8; // 1,048,576
    cvt_f32_bf16_kernel<<<n8 / 256, 256, 0, stream>>>(x, xb, n8);
    rotate_w_kernel<<<dim3(48, 8), 256, 0, stream>>>(attn, qR, kR, vR, filt);
    gemm256_kernel<<<dim3(384), dim3(512), 131072, stream>>>(xb, filt, bias, out);
}